// Round 5
// baseline (386.457 us; speedup 1.0000x reference)
//
#include <hip/hip_runtime.h>
#include <hip/hip_bf16.h>
#include <math.h>

#define HEADS 8
#define D_IN 128
#define D_HEAD 16
#define D_OUT 128  // HEADS * D_HEAD

typedef unsigned short ushort_t;
typedef unsigned int uint_t;
typedef __attribute__((ext_vector_type(8))) short short8;
typedef __attribute__((ext_vector_type(4))) float floatx4;

// ---------------- helpers ----------------
static __device__ inline uint_t f32_to_bf16(float f) {
    uint_t u = __float_as_uint(f);
    return (u + 0x7fffu + ((u >> 16) & 1u)) >> 16;  // RTNE
}
static __device__ inline uint_t pack_bf16(float lo, float hi) {
    return (f32_to_bf16(hi) << 16) | f32_to_bf16(lo);
}
static __device__ inline float bf_lo(uint_t p) { return __uint_as_float(p << 16); }
static __device__ inline float bf_hi(uint_t p) { return __uint_as_float(p & 0xffff0000u); }

// ---------------- kernel 0: prep = W->fragment-major bf16  +  CSR row_ptr ----
// Wfrag layout: t = (((ct*4+ks)*64)+lane)*8 + j holds bf16(W[ct][ks*32+(lane>>4)*8+j][lane&15])
// rowptr: edge-parallel boundary detection over sorted src.
#define PREP_WBLOCKS 64
__global__ __launch_bounds__(256) void prep_kernel(
    const float* __restrict__ Wg, ushort_t* __restrict__ Wfrag,
    const int* __restrict__ src, int* __restrict__ row_ptr, int n, int e)
{
    if (blockIdx.x < PREP_WBLOCKS) {
        int t = blockIdx.x * 256 + threadIdx.x;   // 0..16383
        int j    = t & 7;
        int lane = (t >> 3) & 63;
        int ks   = (t >> 9) & 3;
        int ct   = t >> 11;
        int k = ks * 32 + (lane >> 4) * 8 + j;
        int m = lane & 15;
        float v = Wg[(size_t)ct * (D_IN * D_HEAD) + k * D_HEAD + m];
        Wfrag[t] = (ushort_t)f32_to_bf16(v);
    } else {
        int i = (blockIdx.x - PREP_WBLOCKS) * 256 + threadIdx.x;  // 0..e
        if (i > e) return;
        int sp = (i == 0) ? -1 : src[i - 1];
        int sc = (i == e) ? n  : src[i];
        for (int node = sp + 1; node <= sc; ++node) row_ptr[node] = i;
    }
}

// ---------------- kernel 1: MFMA GEMM + f1/f2 epilogue (HEAD-MAJOR outputs) ----
// feats_h[h][node][16] bf16;  f1_h[h][node], f2_h[h][node] fp32.
__global__ __launch_bounds__(256) void gemm_feats_mfma(
    const float* __restrict__ x, const ushort_t* __restrict__ Wfrag,
    const float* __restrict__ a1, const float* __restrict__ b1,
    const float* __restrict__ a2, const float* __restrict__ b2,
    ushort_t* __restrict__ feats, float* __restrict__ f1,
    float* __restrict__ f2, int n)
{
    __shared__ ushort_t Xs[128][136];  // row stride 272 B (16B-aligned, 2-way banks only)

    const int tid  = threadIdx.x;
    const int wave = tid >> 6;
    const int lane = tid & 63;
    const int row0 = blockIdx.x * 128;

    // ---- stage x tile (fp32 -> bf16), fully coalesced 16 B/lane ----
#pragma unroll
    for (int it = 0; it < 16; ++it) {
        int idx = it * 256 + tid;        // float4 id, 0..4095 (128 rows x 32)
        int r   = idx >> 5;
        int c4  = (idx & 31) * 4;
        float4 v = make_float4(0.f, 0.f, 0.f, 0.f);
        if (row0 + r < n) v = *(const float4*)(x + (size_t)(row0 + r) * D_IN + c4);
        *(uint2*)&Xs[r][c4] = make_uint2(pack_bf16(v.x, v.y), pack_bf16(v.z, v.w));
    }
    __syncthreads();

    const int m  = lane & 15;
    const int kg = lane >> 4;

    floatx4 acc[2][8];
#pragma unroll
    for (int nt = 0; nt < 2; ++nt)
#pragma unroll
        for (int ct = 0; ct < 8; ++ct) acc[nt][ct] = (floatx4){0.f, 0.f, 0.f, 0.f};

#pragma unroll
    for (int ks = 0; ks < 4; ++ks) {
        short8 xb0 = *(const short8*)&Xs[wave * 32 + m][ks * 32 + kg * 8];
        short8 xb1 = *(const short8*)&Xs[wave * 32 + 16 + m][ks * 32 + kg * 8];
#pragma unroll
        for (int ct = 0; ct < 8; ++ct) {
            short8 wa = *(const short8*)(Wfrag + ((size_t)(ct * 4 + ks) * 64 + lane) * 8);
            acc[0][ct] = __builtin_amdgcn_mfma_f32_16x16x32_bf16(wa, xb0, acc[0][ct], 0, 0, 0);
            acc[1][ct] = __builtin_amdgcn_mfma_f32_16x16x32_bf16(wa, xb1, acc[1][ct], 0, 0, 0);
        }
    }

    // ---- epilogue (head-major stores) ----
#pragma unroll
    for (int nt = 0; nt < 2; ++nt) {
        const int node = row0 + wave * 32 + nt * 16 + m;
        const bool valid = node < n;
        if (valid) {
#pragma unroll
            for (int ct = 0; ct < 8; ++ct) {
                uint_t lo = pack_bf16(acc[nt][ct][0], acc[nt][ct][1]);
                uint_t hi = pack_bf16(acc[nt][ct][2], acc[nt][ct][3]);
                *(uint2*)(feats + ((size_t)ct * n + node) * D_HEAD + kg * 4) =
                    make_uint2(lo, hi);
            }
        }
#pragma unroll
        for (int ct = 0; ct < 8; ++ct) {
            float4 A1 = *(const float4*)(a1 + ct * D_HEAD + kg * 4);
            float4 A2 = *(const float4*)(a2 + ct * D_HEAD + kg * 4);
            float p1 = acc[nt][ct][0] * A1.x + acc[nt][ct][1] * A1.y +
                       acc[nt][ct][2] * A1.z + acc[nt][ct][3] * A1.w;
            float p2 = acc[nt][ct][0] * A2.x + acc[nt][ct][1] * A2.y +
                       acc[nt][ct][2] * A2.z + acc[nt][ct][3] * A2.w;
            p1 += __shfl_xor(p1, 16); p1 += __shfl_xor(p1, 32);
            p2 += __shfl_xor(p2, 16); p2 += __shfl_xor(p2, 32);
            if (kg == 0 && valid) {
                f1[(size_t)ct * n + node] = p1 + b1[ct];
                f2[(size_t)ct * n + node] = p2 + b2[ct];
            }
        }
    }
}

// ---------------- kernel 2: head-sliced aggregation, XCD-affine ----------------
// block: head hh = blockIdx%8 (-> XCD hh by round-robin heuristic), 16 nodes.
// wave: 4 consecutive nodes. lane: edge slot q=lane>>3, channel pair cp=lane&7.
// Per-XCD working set = feats_h slice (3.2 MB) + f2_h (0.4 MB) -> L2-resident.
__global__ __launch_bounds__(256) void aggregate_kernel(
    const int* __restrict__ row_ptr, const int* __restrict__ dst,
    const ushort_t* __restrict__ feats,
    const float* __restrict__ f1, const float* __restrict__ f2,
    float* __restrict__ out, int n)
{
    const int hh    = blockIdx.x & 7;
    const int chunk = blockIdx.x >> 3;
    const int wave  = threadIdx.x >> 6;
    const int lane  = threadIdx.x & 63;
    const int q     = lane >> 3;
    const int cp    = lane & 7;

    const float*    f1h = f1 + (size_t)hh * n;
    const float*    f2h = f2 + (size_t)hh * n;
    const ushort_t* fh  = feats + (size_t)hh * n * D_HEAD + cp * 2;

#pragma unroll
    for (int i = 0; i < 4; ++i) {
        const int node = chunk * 16 + wave * 4 + i;
        if (node >= n) break;
        const int start = row_ptr[node];
        const int end   = row_ptr[node + 1];
        const float f1v = f1h[node];

        float s = 0.f, ax = 0.f, ay = 0.f;
        for (int e = start; e < end; e += 8) {
            const int rem = end - e;
            const int qq  = (q < rem) ? q : rem - 1;
            const int d   = dst[e + qq];
            const float g = f2h[d];
            float z = f1v + g;
            z = fmaxf(z, 0.2f * z);                 // leaky_relu(0.2)
            const float w = (q < rem) ? __expf(z) : 0.f;
            const uint_t p = *(const uint_t*)(fh + (size_t)d * D_HEAD);
            s += w;
            ax = fmaf(w, bf_lo(p), ax);
            ay = fmaf(w, bf_hi(p), ay);
        }
        // reduce across the 8 edge slots
        s  += __shfl_xor(s, 8);  s  += __shfl_xor(s, 16);  s  += __shfl_xor(s, 32);
        ax += __shfl_xor(ax, 8); ax += __shfl_xor(ax, 16); ax += __shfl_xor(ax, 32);
        ay += __shfl_xor(ay, 8); ay += __shfl_xor(ay, 16); ay += __shfl_xor(ay, 32);

        if (q == 0) {
            float rx = 0.f, ry = 0.f;
            if (end > start) {
                rx = ax / s;
                ry = ay / s;
                rx = rx > 0.f ? rx : expm1f(rx);    // elu
                ry = ry > 0.f ? ry : expm1f(ry);
            }
            *(float2*)(out + (size_t)node * D_OUT + hh * D_HEAD + cp * 2) =
                make_float2(rx, ry);
        }
    }
}

// ---------------- launch ----------------
extern "C" void kernel_launch(void* const* d_in, const int* in_sizes, int n_in,
                              void* d_out, int out_size, void* d_ws, size_t ws_size,
                              hipStream_t stream)
{
    const float* x  = (const float*)d_in[0];
    const float* W  = (const float*)d_in[1];
    const float* a1 = (const float*)d_in[2];
    const float* b1 = (const float*)d_in[3];
    const float* a2 = (const float*)d_in[4];
    const float* b2 = (const float*)d_in[5];
    const int* src  = (const int*)d_in[6];
    const int* dst  = (const int*)d_in[7];
    float* out = (float*)d_out;

    const int n = in_sizes[0] / D_IN;   // 100000
    const int e = in_sizes[6];          // 1600000

    // workspace carve-up
    char* ws = (char*)d_ws;
    size_t off = 0;
    ushort_t* feats = (ushort_t*)(ws + off);                   // [H][n][16] bf16
    off += (size_t)HEADS * n * D_HEAD * sizeof(ushort_t); off = (off + 255) & ~(size_t)255;
    float* f1 = (float*)(ws + off);                            // [H][n]
    off += (size_t)HEADS * n * sizeof(float);             off = (off + 255) & ~(size_t)255;
    float* f2 = (float*)(ws + off);                            // [H][n]
    off += (size_t)HEADS * n * sizeof(float);             off = (off + 255) & ~(size_t)255;
    int* row_ptr = (int*)(ws + off);
    off += (size_t)(n + 1) * sizeof(int);                 off = (off + 255) & ~(size_t)255;
    ushort_t* Wfrag = (ushort_t*)(ws + off);

    dim3 blk(256);
    const int rp_blocks = (e + 1 + 255) / 256;
    prep_kernel<<<dim3(PREP_WBLOCKS + rp_blocks), blk, 0, stream>>>(
        W, Wfrag, src, row_ptr, n, e);
    gemm_feats_mfma<<<dim3((n + 127) / 128), blk, 0, stream>>>(
        x, Wfrag, a1, b1, a2, b2, feats, f1, f2, n);
    const int node_chunks = (n + 15) / 16;
    aggregate_kernel<<<dim3(8 * node_chunks), blk, 0, stream>>>(
        row_ptr, dst, feats, f1, f2, out, n);
}

// Round 6
// 216.693 us; speedup vs baseline: 1.7834x; 1.7834x over previous
//
#include <hip/hip_runtime.h>
#include <hip/hip_bf16.h>
#include <math.h>

#define HEADS 8
#define D_IN 128
#define D_HEAD 16
#define D_OUT 128  // HEADS * D_HEAD

typedef unsigned short ushort_t;
typedef unsigned int uint_t;
typedef __attribute__((ext_vector_type(8))) short short8;
typedef __attribute__((ext_vector_type(4))) float floatx4;

// ---------------- helpers ----------------
static __device__ inline uint_t f32_to_bf16(float f) {
    uint_t u = __float_as_uint(f);
    return (u + 0x7fffu + ((u >> 16) & 1u)) >> 16;  // RTNE
}
static __device__ inline uint_t pack_bf16(float lo, float hi) {
    return (f32_to_bf16(hi) << 16) | f32_to_bf16(lo);
}
static __device__ inline float bf_lo(uint_t p) { return __uint_as_float(p << 16); }
static __device__ inline float bf_hi(uint_t p) { return __uint_as_float(p & 0xffff0000u); }

// ---------------- kernel 0: prep ----------------
// (a) Wfrag tiles ct=0..7: t = (((ct*4+ks)*64)+lane)*8 + j holds
//     bf16(W[ct][ks*32+(lane>>4)*8+j][lane&15])
// (b) Wfrag tile ct=8 (attention tile): channel m<8 -> dot(W[m][k][:],a1[m]),
//     m>=8 -> dot(W[m-8][k][:],a2[m-8])  => f1/f2 fall out of the main MFMA.
// (c) rowptr: edge-parallel boundary detection over sorted src.
#define PREP_WBLOCKS 64
__global__ __launch_bounds__(256) void prep_kernel(
    const float* __restrict__ Wg,
    const float* __restrict__ a1, const float* __restrict__ a2,
    ushort_t* __restrict__ Wfrag,
    const int* __restrict__ src, int* __restrict__ row_ptr, int n, int e)
{
    const int rp_blocks = (e + 1 + 255) / 256;
    const int bid = blockIdx.x;
    if (bid < PREP_WBLOCKS) {
        int t = bid * 256 + threadIdx.x;   // 0..16383
        int j    = t & 7;
        int lane = (t >> 3) & 63;
        int ks   = (t >> 9) & 3;
        int ct   = t >> 11;
        int k = ks * 32 + (lane >> 4) * 8 + j;
        int m = lane & 15;
        float v = Wg[(size_t)ct * (D_IN * D_HEAD) + k * D_HEAD + m];
        Wfrag[t] = (ushort_t)f32_to_bf16(v);
    } else if (bid < PREP_WBLOCKS + rp_blocks) {
        int i = (bid - PREP_WBLOCKS) * 256 + threadIdx.x;  // 0..e
        if (i > e) return;
        int sp = (i == 0) ? -1 : src[i - 1];
        int sc = (i == e) ? n  : src[i];
        for (int node = sp + 1; node <= sc; ++node) row_ptr[node] = i;
    } else {
        // attention tile: 2048 elements, 8 per thread
#pragma unroll
        for (int i = 0; i < 8; ++i) {
            int t = i * 256 + threadIdx.x;       // 0..2047
            int j  = t & 7;
            int ln = (t >> 3) & 63;
            int ks = (t >> 9) & 3;
            int k  = ks * 32 + (ln >> 4) * 8 + j;
            int mm = ln & 15;
            int h  = mm & 7;
            const float* wrow = Wg + (size_t)h * (D_IN * D_HEAD) + k * D_HEAD;
            const float* av   = (mm < 8 ? a1 : a2) + h * D_HEAD;
            float s = 0.f;
#pragma unroll
            for (int o = 0; o < D_HEAD; ++o) s = fmaf(wrow[o], av[o], s);
            Wfrag[8 * 2048 + t] = (ushort_t)f32_to_bf16(s);
        }
    }
}

// ---------------- kernel 1: MFMA GEMM, LDS-staged W, fused f1/f2 tile ----------
// Block: 256 thr = 4 waves; tile = 64 nodes x (128 feat-ch + 16 attn-ch).
// Wave = 16 nodes. All W fragments in LDS (36 KB), Xs 17 KB -> 54 KB/block.
__global__ __launch_bounds__(256) void gemm_feats_mfma(
    const float* __restrict__ x, const ushort_t* __restrict__ Wfrag,
    const float* __restrict__ b1, const float* __restrict__ b2,
    ushort_t* __restrict__ feats, float* __restrict__ f1,
    float* __restrict__ f2, int n)
{
    __shared__ ushort_t Xs[64][136];      // row stride 272 B
    __shared__ ushort_t WsF[9 * 2048];    // fragment-major, ds_read_b128-ready

    const int tid  = threadIdx.x;
    const int wave = tid >> 6;
    const int lane = tid & 63;
    const int row0 = blockIdx.x * 64;

    // ---- stage W fragments: 2304 uint4, 9 per thread, coalesced ----
    {
        const uint4* wsrc = (const uint4*)Wfrag;
        uint4*       wdst = (uint4*)WsF;
#pragma unroll
        for (int i = 0; i < 9; ++i) wdst[i * 256 + tid] = wsrc[i * 256 + tid];
    }
    // ---- stage x tile (fp32 -> bf16), coalesced ----
#pragma unroll
    for (int it = 0; it < 8; ++it) {
        int idx = it * 256 + tid;        // float4 id, 0..2047 (64 rows x 32)
        int r   = idx >> 5;
        int c4  = (idx & 31) * 4;
        float4 v = make_float4(0.f, 0.f, 0.f, 0.f);
        if (row0 + r < n) v = *(const float4*)(x + (size_t)(row0 + r) * D_IN + c4);
        *(uint2*)&Xs[r][c4] = make_uint2(pack_bf16(v.x, v.y), pack_bf16(v.z, v.w));
    }
    __syncthreads();

    const int m  = lane & 15;
    const int kg = lane >> 4;

    floatx4 acc[9];
#pragma unroll
    for (int ct = 0; ct < 9; ++ct) acc[ct] = (floatx4){0.f, 0.f, 0.f, 0.f};

#pragma unroll
    for (int ks = 0; ks < 4; ++ks) {
        short8 xb = *(const short8*)&Xs[wave * 16 + m][ks * 32 + kg * 8];
#pragma unroll
        for (int ct = 0; ct < 9; ++ct) {
            short8 wa = *(const short8*)&WsF[((ct * 4 + ks) * 64 + lane) * 8];
            acc[ct] = __builtin_amdgcn_mfma_f32_16x16x32_bf16(wa, xb, acc[ct], 0, 0, 0);
        }
    }

    // ---- epilogue ----
    // D layout: col(lane&15)=node within wave tile; row=kg*4+reg=channel in tile.
    const int node = row0 + wave * 16 + m;
    if (node < n) {
#pragma unroll
        for (int ct = 0; ct < 8; ++ct) {
            uint_t lo = pack_bf16(acc[ct][0], acc[ct][1]);
            uint_t hi = pack_bf16(acc[ct][2], acc[ct][3]);
            *(uint2*)(feats + (size_t)node * D_OUT + ct * 16 + kg * 4) = make_uint2(lo, hi);
        }
        // attention tile: kg0/1 -> f1 heads 0-3/4-7; kg2/3 -> f2 heads 0-3/4-7
        const float* bb = (kg < 2) ? b1 : b2;
        float4 bv = *(const float4*)(bb + (kg & 1) * 4);
        float4 o = make_float4(acc[8][0] + bv.x, acc[8][1] + bv.y,
                               acc[8][2] + bv.z, acc[8][3] + bv.w);
        float* dstp = ((kg < 2) ? f1 : f2) + (size_t)node * HEADS + (kg & 1) * 4;
        *(float4*)dstp = o;
    }
}

// ---------------- kernel 2: per-node aggregation (R4 structure) ----------------
// one wave per node; lane owns out channels (2*lane, 2*lane+1); head = lane>>3.
// Weight de-dup: lane (h=l>>3,q=l&7) computes w for edge q / head h, shfl-bcast.
__global__ __launch_bounds__(256) void aggregate_kernel(
    const int* __restrict__ row_ptr, const int* __restrict__ dst,
    const ushort_t* __restrict__ feats,
    const float* __restrict__ f1, const float* __restrict__ f2,
    float* __restrict__ out, int n)
{
    int node = blockIdx.x * 4 + (threadIdx.x >> 6);
    node = __builtin_amdgcn_readfirstlane(node);   // wave-uniform -> scalar loads
    if (node >= n) return;
    const int lane = threadIdx.x & 63;
    const int h = lane >> 3;

    const float f1v   = f1[(size_t)node * HEADS + h];
    const int   start = row_ptr[node];
    const int   end   = row_ptr[node + 1];

    const ushort_t* fl = feats + 2 * lane;

    float s = 0.f, ax = 0.f, ay = 0.f;
    int e = start;
    for (; e + 8 <= end; e += 8) {
        int d[8];
#pragma unroll
        for (int q = 0; q < 8; ++q) d[q] = dst[e + q];          // scalar loads
        const int   dq = dst[e + (lane & 7)];                   // vector load
        const float g  = f2[(size_t)dq * HEADS + h];
        float z = f1v + g;
        z = fmaxf(z, 0.2f * z);                                 // leaky_relu
        const float w = __expf(z);
        uint_t p[8];
#pragma unroll
        for (int q = 0; q < 8; ++q)
            p[q] = *(const uint_t*)(fl + (size_t)d[q] * D_OUT); // saddr gathers
#pragma unroll
        for (int q = 0; q < 8; ++q) {
            const float wq = __shfl(w, (lane & 56) | q);
            s += wq;
            ax = fmaf(wq, bf_lo(p[q]), ax);
            ay = fmaf(wq, bf_hi(p[q]), ay);
        }
    }
    for (; e < end; ++e) {
        const int d = dst[e];
        const float g = f2[(size_t)d * HEADS + h];
        const uint_t p = *(const uint_t*)(fl + (size_t)d * D_OUT);
        float z = f1v + g;
        z = fmaxf(z, 0.2f * z);
        const float w = __expf(z);
        s += w;
        ax = fmaf(w, bf_lo(p), ax);
        ay = fmaf(w, bf_hi(p), ay);
    }

    float rx = 0.f, ry = 0.f;
    if (end > start) {
        rx = ax / s;
        ry = ay / s;
        rx = rx > 0.f ? rx : expm1f(rx);   // elu
        ry = ry > 0.f ? ry : expm1f(ry);
    }
    *(float2*)(out + (size_t)node * D_OUT + 2 * lane) = make_float2(rx, ry);
}

// ---------------- launch ----------------
extern "C" void kernel_launch(void* const* d_in, const int* in_sizes, int n_in,
                              void* d_out, int out_size, void* d_ws, size_t ws_size,
                              hipStream_t stream)
{
    const float* x  = (const float*)d_in[0];
    const float* W  = (const float*)d_in[1];
    const float* a1 = (const float*)d_in[2];
    const float* b1 = (const float*)d_in[3];
    const float* a2 = (const float*)d_in[4];
    const float* b2 = (const float*)d_in[5];
    const int* src  = (const int*)d_in[6];
    const int* dst  = (const int*)d_in[7];
    float* out = (float*)d_out;

    const int n = in_sizes[0] / D_IN;   // 100000
    const int e = in_sizes[6];          // 1600000

    // workspace carve-up
    char* ws = (char*)d_ws;
    size_t off = 0;
    ushort_t* feats = (ushort_t*)(ws + off);                // [n][128] bf16
    off += (size_t)n * D_OUT * sizeof(ushort_t); off = (off + 255) & ~(size_t)255;
    float* f1 = (float*)(ws + off);                         // [n][8]
    off += (size_t)n * HEADS * sizeof(float);    off = (off + 255) & ~(size_t)255;
    float* f2 = (float*)(ws + off);                         // [n][8]
    off += (size_t)n * HEADS * sizeof(float);    off = (off + 255) & ~(size_t)255;
    int* row_ptr = (int*)(ws + off);
    off += (size_t)(n + 1) * sizeof(int);        off = (off + 255) & ~(size_t)255;
    ushort_t* Wfrag = (ushort_t*)(ws + off);                // 9*2048 bf16

    dim3 blk(256);
    const int rp_blocks = (e + 1 + 255) / 256;
    prep_kernel<<<dim3(PREP_WBLOCKS + rp_blocks + 1), blk, 0, stream>>>(
        W, a1, a2, Wfrag, src, row_ptr, n, e);
    gemm_feats_mfma<<<dim3((n + 63) / 64), blk, 0, stream>>>(
        x, Wfrag, b1, b2, feats, f1, f2, n);
    aggregate_kernel<<<dim3((n + 3) / 4), blk, 0, stream>>>(
        row_ptr, dst, feats, f1, f2, out, n);
}